// Round 8
// baseline (232.114 us; speedup 1.0000x reference)
//
#include <hip/hip_runtime.h>

#define NN 20000
#define IN_DIM 256
#define HID 128
#define OUT_DIM 64
#define N_LAYERS 4
#define N_PATHS 8
#define PATH_LEN 8
#define N_TYPES 2

typedef __attribute__((ext_vector_type(8))) short bf16x8;
typedef __attribute__((ext_vector_type(4))) float f32x4;

__device__ __forceinline__ float bf2f(ushort u) {
    union { uint u; float f; } c; c.u = ((uint)u) << 16; return c.f;
}
__device__ __forceinline__ ushort f2bf(float f) {
    union { float f; uint u; } c; c.f = f;
    uint u = c.u;
    uint lsb = (u >> 16) & 1;
    u += 0x7fffu + lsb;          // round-to-nearest-even (inputs finite)
    return (ushort)(u >> 16);
}

// ---------------------------------------------------------------------------
// One-shot fp32 -> bf16 conversion of all weight matrices (quad-per-thread).
// ---------------------------------------------------------------------------
__global__ __launch_bounds__(256) void cvt_weights(
    const float* __restrict__ w_in, const float* __restrict__ w_layer,
    const float* __restrict__ w_out,
    ushort* __restrict__ o_in, ushort* __restrict__ o_layer,
    ushort* __restrict__ o_out)
{
    int i = blockIdx.x * 256 + threadIdx.x;
    const float* s; ushort* d; int off;
    if (i < 8192)        { s = w_in;    d = o_in;    off = i; }
    else if (i < 40960)  { s = w_layer; d = o_layer; off = i - 8192; }
    else if (i < 43008)  { s = w_out;   d = o_out;   off = i - 40960; }
    else return;
    float4 v = ((const float4*)s)[off];
    ushort4 o;
    o.x = f2bf(v.x); o.y = f2bf(v.y); o.z = f2bf(v.z); o.w = f2bf(v.w);
    ((ushort4*)d)[off] = o;
}

// ---------------------------------------------------------------------------
// bf16 MFMA GEMM: C = epilogue(A[M,K] @ W[N,K]^T), fp32 accumulate.
// BM=64, BK=64, 4 waves (2x2), wave computes 32 x N/2. MFMA 16x16x32 bf16.
// LDS XOR-swizzle on 16B granules: elem ^= (row&7)<<3 (T2, conflict-free).
// AF32: A operand is fp32 in global, converted to bf16 while staging.
// EPI 0: bf16 out = relu(acc + bias[n])
// EPI 1: bf16 out = 0.8*relu(acc) + 0.1*pre + 0.1*in0
// EPI 2: f32  out = relu(acc + bias[n])
// ---------------------------------------------------------------------------
template <int N, int K, int EPI, bool AF32>
__global__ __launch_bounds__(256) void gemm_mfma(
    const void* __restrict__ Ap,
    const ushort* __restrict__ W,     // [N][K] bf16
    const float* __restrict__ bias,
    const ushort* __restrict__ pre,
    const ushort* __restrict__ in0,
    void* __restrict__ Cout,
    int M)
{
    constexpr int BM = 64, BK = 64;
    constexpr int NC = N / 32;              // 4 (N=128) or 2 (N=64)

    __shared__ short As[BM * BK];
    __shared__ short Ws[N * BK];

    const int tid = threadIdx.x;
    const int lane = tid & 63;
    const int w = tid >> 6;
    const int wr = w >> 1, wc = w & 1;
    const int m0 = blockIdx.x * BM;
    const int l15 = lane & 15, l4 = lane >> 4;

    f32x4 acc[2][NC];
#pragma unroll
    for (int mr = 0; mr < 2; ++mr)
#pragma unroll
        for (int nc = 0; nc < NC; ++nc)
#pragma unroll
            for (int j = 0; j < 4; ++j) acc[mr][nc][j] = 0.f;

    for (int k0 = 0; k0 < K; k0 += BK) {
        // ---- stage A tile ----
#pragma unroll
        for (int c = tid; c < BM * BK / 8; c += 256) {
            int r = c >> 3, kc = c & 7;
            int gr = m0 + r; if (gr >= M) gr = M - 1;   // clamp tail
            bf16x8 v;
            if constexpr (AF32) {
                const float* Af = (const float*)Ap;
                float4 v0 = *(const float4*)(Af + (long)gr * K + k0 + kc * 8);
                float4 v1 = *(const float4*)(Af + (long)gr * K + k0 + kc * 8 + 4);
                v[0] = (short)f2bf(v0.x); v[1] = (short)f2bf(v0.y);
                v[2] = (short)f2bf(v0.z); v[3] = (short)f2bf(v0.w);
                v[4] = (short)f2bf(v1.x); v[5] = (short)f2bf(v1.y);
                v[6] = (short)f2bf(v1.z); v[7] = (short)f2bf(v1.w);
            } else {
                v = *(const bf16x8*)((const ushort*)Ap + (long)gr * K + k0 + kc * 8);
            }
            int di = (r * BK + kc * 8) ^ ((r & 7) << 3);
            *(bf16x8*)&As[di] = v;
        }
        // ---- stage W tile (bf16) ----
#pragma unroll
        for (int c = tid; c < N * BK / 8; c += 256) {
            int r = c >> 3, kc = c & 7;
            bf16x8 v = *(const bf16x8*)(W + (long)r * K + k0 + kc * 8);
            int di = (r * BK + kc * 8) ^ ((r & 7) << 3);
            *(bf16x8*)&Ws[di] = v;
        }
        __syncthreads();

#pragma unroll
        for (int ks = 0; ks < 2; ++ks) {
            bf16x8 av[2], bv[NC];
            const int kk = ks * 32 + l4 * 8;
#pragma unroll
            for (int mr = 0; mr < 2; ++mr) {
                int r = wr * 32 + mr * 16 + l15;
                av[mr] = *(const bf16x8*)&As[(r * BK + kk) ^ ((r & 7) << 3)];
            }
#pragma unroll
            for (int nc = 0; nc < NC; ++nc) {
                int r = wc * (N / 2) + nc * 16 + l15;
                bv[nc] = *(const bf16x8*)&Ws[(r * BK + kk) ^ ((r & 7) << 3)];
            }
#pragma unroll
            for (int mr = 0; mr < 2; ++mr)
#pragma unroll
                for (int nc = 0; nc < NC; ++nc)
                    acc[mr][nc] = __builtin_amdgcn_mfma_f32_16x16x32_bf16(
                        av[mr], bv[nc], acc[mr][nc], 0, 0, 0);
        }
        __syncthreads();
    }

#pragma unroll
    for (int mr = 0; mr < 2; ++mr) {
#pragma unroll
        for (int nc = 0; nc < NC; ++nc) {
            int gn = wc * (N / 2) + nc * 16 + l15;
#pragma unroll
            for (int j = 0; j < 4; ++j) {
                int gm = m0 + wr * 32 + mr * 16 + l4 * 4 + j;
                if (gm >= M) continue;
                float v = acc[mr][nc][j];
                if (EPI == 0) {
                    v += bias[gn];
                    v = fmaxf(v, 0.f);
                    ((ushort*)Cout)[(long)gm * N + gn] = f2bf(v);
                } else if (EPI == 1) {
                    v = fmaxf(v, 0.f);
                    v = 0.8f * v + 0.1f * bf2f(pre[(long)gm * N + gn])
                                 + 0.1f * bf2f(in0[(long)gm * N + gn]);
                    ((ushort*)Cout)[(long)gm * N + gn] = f2bf(v);
                } else {
                    v += bias[gn];
                    v = fmaxf(v, 0.f);
                    ((float*)Cout)[(long)gm * N + gn] = v;
                }
            }
        }
    }
}

// ---------------------------------------------------------------------------
// Gather + unweighted path-sum per (type,l) + weighted combine.
// h_half passed per-DISPATCH: two sequential kernel launches per layer give
// GUARANTEED serialization (stream order), so each launch's feats working set
// is 20000 x 128 B = 2.56 MB < 4 MiB per-XCD L2. paths reads and fout writes
// are nontemporal so streaming traffic doesn't evict the hot feats half.
// Block = 256 thr = 16 nodes x 16 lanes; lane owns 4 channels (uint2 = 8B).
// Type handling via bitmask+popcount (no runtime-indexed reg arrays).
// ---------------------------------------------------------------------------
__global__ __launch_bounds__(256) void gather_bf16(
    const uint* __restrict__ feats_u,   // [NN][64]  (bf16x2 packed)
    const int* __restrict__ paths,      // [P][NN][L]
    const int* __restrict__ ptypes,     // [P]
    const float* __restrict__ pw,       // [2][L][HID] f32
    uint* __restrict__ fout_u,          // [NN][128] (bf16x2 packed)
    int h_half)
{
    const int nbase = (int)blockIdx.x * 16;

    const int tid = threadIdx.x;
    const int node = tid >> 4;          // 0..15
    const int l16 = tid & 15;           // channel quad within the h-half
    const int n = nbase + node;

    __shared__ int idx_l[16][N_TYPES][PATH_LEN][8];

    // type bitmask (bit p = type of path p), counts via popcount
    uint tmask = 0;
#pragma unroll
    for (int p = 0; p < N_PATHS; ++p) tmask |= (uint)(ptypes[p] != 0) << p;
    const int cnt1 = __popc(tmask);
    const int cnt0 = N_PATHS - cnt1;

    // stage 16 nodes x 64 indices, sorted by (type, l, rank); nontemporal
#pragma unroll
    for (int j = 0; j < 4; ++j) {
        int li = tid * 4 + j;           // 0..1023
        int nd = li >> 6, k = li & 63, p = k >> 3, l = k & 7;
        int tp = (int)((tmask >> p) & 1u);
        uint below = tmask & ((1u << p) - 1u);
        int rank = tp ? __popc(below) : p - __popc(below);
        idx_l[nd][tp][l][rank] =
            __builtin_nontemporal_load(&paths[((long)p * NN + nbase + nd) * PATH_LEN + l]);
    }
    __syncthreads();

    const float inv0 = cnt0 ? 1.f / (float)cnt0 : 0.f;
    const float inv1 = cnt1 ? 1.f / (float)cnt1 : 0.f;

    // per-lane weights for both types, pre-scaled by 1/count (static arrays)
    float4 wv[2][PATH_LEN];
#pragma unroll
    for (int e = 0; e < 2; ++e) {
        float s = e ? inv1 : inv0;
#pragma unroll
        for (int l = 0; l < PATH_LEN; ++l) {
            float4 t = *(const float4*)&pw[(e * PATH_LEN + l) * HID + h_half * 64 + l16 * 4];
            wv[e][l].x = t.x * s; wv[e][l].y = t.y * s;
            wv[e][l].z = t.z * s; wv[e][l].w = t.w * s;
        }
    }

    const long coff = h_half * 32 + l16 * 2;   // uint offset within a row
    float4 acc[2];
#pragma unroll
    for (int e = 0; e < 2; ++e) {
        acc[e].x = acc[e].y = acc[e].z = acc[e].w = 0.f;
        const int ce = e ? cnt1 : cnt0;
        if (ce == 4) {
#pragma unroll
            for (int l = 0; l < PATH_LEN; ++l) {
                int4 r4 = *(const int4*)&idx_l[node][e][l][0];
                uint2 v0 = *(const uint2*)(feats_u + (long)r4.x * 64 + coff);
                uint2 v1 = *(const uint2*)(feats_u + (long)r4.y * 64 + coff);
                uint2 v2 = *(const uint2*)(feats_u + (long)r4.z * 64 + coff);
                uint2 v3 = *(const uint2*)(feats_u + (long)r4.w * 64 + coff);
                float sx = bf2f((ushort)(v0.x & 0xffff)) + bf2f((ushort)(v1.x & 0xffff))
                         + bf2f((ushort)(v2.x & 0xffff)) + bf2f((ushort)(v3.x & 0xffff));
                float sy = bf2f((ushort)(v0.x >> 16)) + bf2f((ushort)(v1.x >> 16))
                         + bf2f((ushort)(v2.x >> 16)) + bf2f((ushort)(v3.x >> 16));
                float sz = bf2f((ushort)(v0.y & 0xffff)) + bf2f((ushort)(v1.y & 0xffff))
                         + bf2f((ushort)(v2.y & 0xffff)) + bf2f((ushort)(v3.y & 0xffff));
                float sw = bf2f((ushort)(v0.y >> 16)) + bf2f((ushort)(v1.y >> 16))
                         + bf2f((ushort)(v2.y >> 16)) + bf2f((ushort)(v3.y >> 16));
                acc[e].x += sx * wv[e][l].x;
                acc[e].y += sy * wv[e][l].y;
                acc[e].z += sz * wv[e][l].z;
                acc[e].w += sw * wv[e][l].w;
            }
        } else {
            // generic fallback for any type distribution
#pragma unroll
            for (int l = 0; l < PATH_LEN; ++l) {
                float sx = 0.f, sy = 0.f, sz = 0.f, sw = 0.f;
                for (int q = 0; q < ce; ++q) {
                    int row = idx_l[node][e][l][q];
                    uint2 v = *(const uint2*)(feats_u + (long)row * 64 + coff);
                    sx += bf2f((ushort)(v.x & 0xffff));
                    sy += bf2f((ushort)(v.x >> 16));
                    sz += bf2f((ushort)(v.y & 0xffff));
                    sw += bf2f((ushort)(v.y >> 16));
                }
                acc[e].x += sx * wv[e][l].x;
                acc[e].y += sy * wv[e][l].y;
                acc[e].z += sz * wv[e][l].z;
                acc[e].w += sw * wv[e][l].w;
            }
        }
    }

#pragma unroll
    for (int e = 0; e < 2; ++e) {
        uint2 o;
        o.x = (uint)f2bf(acc[e].x) | ((uint)f2bf(acc[e].y) << 16);
        o.y = (uint)f2bf(acc[e].z) | ((uint)f2bf(acc[e].w) << 16);
        unsigned long long packed = (unsigned long long)o.x
                                  | ((unsigned long long)o.y << 32);
        __builtin_nontemporal_store(packed,
            (unsigned long long*)(fout_u + (long)n * 128 + e * 64 + coff));
    }
}

// ---------------------------------------------------------------------------
extern "C" void kernel_launch(void* const* d_in, const int* in_sizes, int n_in,
                              void* d_out, int out_size, void* d_ws, size_t ws_size,
                              hipStream_t stream)
{
    const float* input_x      = (const float*)d_in[0];
    const int*   paths        = (const int*)d_in[1];
    const int*   path_types   = (const int*)d_in[2];
    const float* fc_in_w      = (const float*)d_in[3];
    const float* fc_in_b      = (const float*)d_in[4];
    const float* fc_out_w     = (const float*)d_in[5];
    const float* fc_out_b     = (const float*)d_in[6];
    const float* layer_fc_w   = (const float*)d_in[7];
    const float* path_weights = (const float*)d_in[8];
    float* out = (float*)d_out;

    char* p = (char*)d_ws;
    ushort* w_in     = (ushort*)p; p += HID * IN_DIM * 2;                   // 64 KB
    ushort* w_layer  = (ushort*)p; p += N_LAYERS * HID * N_TYPES * HID * 2; // 256 KB
    ushort* w_out    = (ushort*)p; p += OUT_DIM * HID * 2;                  // 16 KB
    ushort* in_feats = (ushort*)p; p += (long)NN * HID * 2;                 // 5.12 MB
    ushort* featsA   = (ushort*)p; p += (long)NN * HID * 2;
    ushort* featsB   = (ushort*)p; p += (long)NN * HID * 2;
    ushort* fout     = (ushort*)p; p += (long)NN * N_TYPES * HID * 2;       // 10.24 MB

    cvt_weights<<<168, 256, 0, stream>>>(fc_in_w, layer_fc_w, fc_out_w,
                                         w_in, w_layer, w_out);

    const int GG = (NN + 63) / 64;       // 313
    const int GTILES = NN / 16;          // 1250 per half

    gemm_mfma<HID, IN_DIM, 0, true><<<GG, 256, 0, stream>>>(
        input_x, w_in, fc_in_b, nullptr, nullptr, in_feats, NN);

    const ushort* src = in_feats;
    ushort* dsts[N_LAYERS] = {featsA, featsB, featsA, featsB};
    for (int i = 0; i < N_LAYERS; ++i) {
        // two sequential half-dispatches: forced L2 residency of each
        // 2.56 MB feats half
        gather_bf16<<<GTILES, 256, 0, stream>>>(
            (const uint*)src, paths, path_types,
            path_weights + (long)i * N_TYPES * PATH_LEN * HID, (uint*)fout, 0);
        gather_bf16<<<GTILES, 256, 0, stream>>>(
            (const uint*)src, paths, path_types,
            path_weights + (long)i * N_TYPES * PATH_LEN * HID, (uint*)fout, 1);
        gemm_mfma<HID, N_TYPES * HID, 1, false><<<GG, 256, 0, stream>>>(
            fout, w_layer + (long)i * HID * N_TYPES * HID, nullptr,
            src, in_feats, dsts[i], NN);
        src = dsts[i];
    }

    gemm_mfma<OUT_DIM, HID, 2, false><<<GG, 256, 0, stream>>>(
        src, w_out, fc_out_b, nullptr, nullptr, out, NN);
}

// Round 9
// 202.395 us; speedup vs baseline: 1.1468x; 1.1468x over previous
//
#include <hip/hip_runtime.h>

#define NN 20000
#define IN_DIM 256
#define HID 128
#define OUT_DIM 64
#define N_LAYERS 4
#define N_PATHS 8
#define PATH_LEN 8
#define N_TYPES 2

typedef __attribute__((ext_vector_type(8))) short bf16x8;
typedef __attribute__((ext_vector_type(4))) float f32x4;

__device__ __forceinline__ float bf2f(ushort u) {
    union { uint u; float f; } c; c.u = ((uint)u) << 16; return c.f;
}
__device__ __forceinline__ ushort f2bf(float f) {
    union { float f; uint u; } c; c.f = f;
    uint u = c.u;
    uint lsb = (u >> 16) & 1;
    u += 0x7fffu + lsb;          // round-to-nearest-even (inputs finite)
    return (ushort)(u >> 16);
}

// ---------------------------------------------------------------------------
// One-shot fp32 -> bf16 conversion of all weight matrices (quad-per-thread).
// ---------------------------------------------------------------------------
__global__ __launch_bounds__(256) void cvt_weights(
    const float* __restrict__ w_in, const float* __restrict__ w_layer,
    const float* __restrict__ w_out,
    ushort* __restrict__ o_in, ushort* __restrict__ o_layer,
    ushort* __restrict__ o_out)
{
    int i = blockIdx.x * 256 + threadIdx.x;
    const float* s; ushort* d; int off;
    if (i < 8192)        { s = w_in;    d = o_in;    off = i; }
    else if (i < 40960)  { s = w_layer; d = o_layer; off = i - 8192; }
    else if (i < 43008)  { s = w_out;   d = o_out;   off = i - 40960; }
    else return;
    float4 v = ((const float4*)s)[off];
    ushort4 o;
    o.x = f2bf(v.x); o.y = f2bf(v.y); o.z = f2bf(v.z); o.w = f2bf(v.w);
    ((ushort4*)d)[off] = o;
}

// ---------------------------------------------------------------------------
// bf16 MFMA GEMM: C = epilogue(A[M,K] @ W[N,K]^T), fp32 accumulate.
// BM=64, BK=64, 4 waves (2x2), wave computes 32 x N/2. MFMA 16x16x32 bf16.
// LDS XOR-swizzle on 16B granules: elem ^= (row&7)<<3 (T2, conflict-free).
// AF32: A operand is fp32 in global, converted to bf16 while staging.
// EPI 0: bf16 out = relu(acc + bias[n])
// EPI 1: bf16 out = 0.8*relu(acc) + 0.1*pre + 0.1*in0
// EPI 2: f32  out = relu(acc + bias[n])
// ---------------------------------------------------------------------------
template <int N, int K, int EPI, bool AF32>
__global__ __launch_bounds__(256) void gemm_mfma(
    const void* __restrict__ Ap,
    const ushort* __restrict__ W,     // [N][K] bf16
    const float* __restrict__ bias,
    const ushort* __restrict__ pre,
    const ushort* __restrict__ in0,
    void* __restrict__ Cout,
    int M)
{
    constexpr int BM = 64, BK = 64;
    constexpr int NC = N / 32;              // 4 (N=128) or 2 (N=64)

    __shared__ short As[BM * BK];
    __shared__ short Ws[N * BK];

    const int tid = threadIdx.x;
    const int lane = tid & 63;
    const int w = tid >> 6;
    const int wr = w >> 1, wc = w & 1;
    const int m0 = blockIdx.x * BM;
    const int l15 = lane & 15, l4 = lane >> 4;

    f32x4 acc[2][NC];
#pragma unroll
    for (int mr = 0; mr < 2; ++mr)
#pragma unroll
        for (int nc = 0; nc < NC; ++nc)
#pragma unroll
            for (int j = 0; j < 4; ++j) acc[mr][nc][j] = 0.f;

    for (int k0 = 0; k0 < K; k0 += BK) {
        // ---- stage A tile ----
#pragma unroll
        for (int c = tid; c < BM * BK / 8; c += 256) {
            int r = c >> 3, kc = c & 7;
            int gr = m0 + r; if (gr >= M) gr = M - 1;   // clamp tail
            bf16x8 v;
            if constexpr (AF32) {
                const float* Af = (const float*)Ap;
                float4 v0 = *(const float4*)(Af + (long)gr * K + k0 + kc * 8);
                float4 v1 = *(const float4*)(Af + (long)gr * K + k0 + kc * 8 + 4);
                v[0] = (short)f2bf(v0.x); v[1] = (short)f2bf(v0.y);
                v[2] = (short)f2bf(v0.z); v[3] = (short)f2bf(v0.w);
                v[4] = (short)f2bf(v1.x); v[5] = (short)f2bf(v1.y);
                v[6] = (short)f2bf(v1.z); v[7] = (short)f2bf(v1.w);
            } else {
                v = *(const bf16x8*)((const ushort*)Ap + (long)gr * K + k0 + kc * 8);
            }
            int di = (r * BK + kc * 8) ^ ((r & 7) << 3);
            *(bf16x8*)&As[di] = v;
        }
        // ---- stage W tile (bf16) ----
#pragma unroll
        for (int c = tid; c < N * BK / 8; c += 256) {
            int r = c >> 3, kc = c & 7;
            bf16x8 v = *(const bf16x8*)(W + (long)r * K + k0 + kc * 8);
            int di = (r * BK + kc * 8) ^ ((r & 7) << 3);
            *(bf16x8*)&Ws[di] = v;
        }
        __syncthreads();

#pragma unroll
        for (int ks = 0; ks < 2; ++ks) {
            bf16x8 av[2], bv[NC];
            const int kk = ks * 32 + l4 * 8;
#pragma unroll
            for (int mr = 0; mr < 2; ++mr) {
                int r = wr * 32 + mr * 16 + l15;
                av[mr] = *(const bf16x8*)&As[(r * BK + kk) ^ ((r & 7) << 3)];
            }
#pragma unroll
            for (int nc = 0; nc < NC; ++nc) {
                int r = wc * (N / 2) + nc * 16 + l15;
                bv[nc] = *(const bf16x8*)&Ws[(r * BK + kk) ^ ((r & 7) << 3)];
            }
#pragma unroll
            for (int mr = 0; mr < 2; ++mr)
#pragma unroll
                for (int nc = 0; nc < NC; ++nc)
                    acc[mr][nc] = __builtin_amdgcn_mfma_f32_16x16x32_bf16(
                        av[mr], bv[nc], acc[mr][nc], 0, 0, 0);
        }
        __syncthreads();
    }

#pragma unroll
    for (int mr = 0; mr < 2; ++mr) {
#pragma unroll
        for (int nc = 0; nc < NC; ++nc) {
            int gn = wc * (N / 2) + nc * 16 + l15;
#pragma unroll
            for (int j = 0; j < 4; ++j) {
                int gm = m0 + wr * 32 + mr * 16 + l4 * 4 + j;
                if (gm >= M) continue;
                float v = acc[mr][nc][j];
                if (EPI == 0) {
                    v += bias[gn];
                    v = fmaxf(v, 0.f);
                    ((ushort*)Cout)[(long)gm * N + gn] = f2bf(v);
                } else if (EPI == 1) {
                    v = fmaxf(v, 0.f);
                    v = 0.8f * v + 0.1f * bf2f(pre[(long)gm * N + gn])
                                 + 0.1f * bf2f(in0[(long)gm * N + gn]);
                    ((ushort*)Cout)[(long)gm * N + gn] = f2bf(v);
                } else {
                    v += bias[gn];
                    v = fmaxf(v, 0.f);
                    ((float*)Cout)[(long)gm * N + gn] = v;
                }
            }
        }
    }
}

// ---------------------------------------------------------------------------
// Gather, MLP-maximized. Round-7 launch structure (grid = 2*(NN/16), block =
// 16 nodes x 16 lanes, h_half = blockIdx / 1250). Changes for latency hiding:
//  - pre-scaled weights live in LDS (4 KB), not 64 VGPRs
//  - fast path: prefetch all 8 index-int4s, then issue 16 independent
//    global loads per batch into static-indexed register arrays BEFORE any
//    consumption (2 batches per type)
//  - __launch_bounds__(256,4): VGPR cap 128, compiler free to keep ~16
//    loads in flight per wave
// ---------------------------------------------------------------------------
__global__ __launch_bounds__(256, 4) void gather_bf16(
    const uint* __restrict__ feats_u,   // [NN][64]  (bf16x2 packed)
    const int* __restrict__ paths,      // [P][NN][L]
    const int* __restrict__ ptypes,     // [P]
    const float* __restrict__ pw,       // [2][L][HID] f32
    uint* __restrict__ fout_u)          // [NN][128] (bf16x2 packed)
{
    const int gb = (int)blockIdx.x;
    const int h_half = gb / (NN / 16);
    const int ntile = gb % (NN / 16);
    const int nbase = ntile * 16;

    const int tid = threadIdx.x;
    const int node = tid >> 4;          // 0..15
    const int l16 = tid & 15;           // channel quad within the h-half
    const int n = nbase + node;

    __shared__ int idx_l[16][N_TYPES][PATH_LEN][8];     // 8 KB
    __shared__ float wls[N_TYPES][PATH_LEN][64];        // 4 KB, pre-scaled

    // type bitmask (bit p = type of path p), counts via popcount
    uint tmask = 0;
#pragma unroll
    for (int p = 0; p < N_PATHS; ++p) tmask |= (uint)(ptypes[p] != 0) << p;
    const int cnt1 = __popc(tmask);
    const int cnt0 = N_PATHS - cnt1;
    const float inv0 = cnt0 ? 1.f / (float)cnt0 : 0.f;
    const float inv1 = cnt1 ? 1.f / (float)cnt1 : 0.f;

    // stage 16 nodes x 64 indices, sorted by (type, l, rank); nontemporal
#pragma unroll
    for (int j = 0; j < 4; ++j) {
        int li = tid * 4 + j;           // 0..1023
        int nd = li >> 6, k = li & 63, p = k >> 3, l = k & 7;
        int tp = (int)((tmask >> p) & 1u);
        uint below = tmask & ((1u << p) - 1u);
        int rank = tp ? __popc(below) : p - __popc(below);
        idx_l[nd][tp][l][rank] =
            __builtin_nontemporal_load(&paths[((long)p * NN + nbase + nd) * PATH_LEN + l]);
    }
    // stage pre-scaled weights for this h-half: 256 float4s, 1 per thread
    {
        int e = tid >> 7, l = (tid >> 4) & 7, c4 = tid & 15;
        float s = e ? inv1 : inv0;
        float4 t = *(const float4*)&pw[(e * PATH_LEN + l) * HID + h_half * 64 + c4 * 4];
        t.x *= s; t.y *= s; t.z *= s; t.w *= s;
        *(float4*)&wls[e][l][c4 * 4] = t;
    }
    __syncthreads();

    const long coff = h_half * 32 + l16 * 2;   // uint offset within a row
    float4 out[2];

#pragma unroll
    for (int e = 0; e < 2; ++e) {
        const int ce = e ? cnt1 : cnt0;
        float4 acc = {0.f, 0.f, 0.f, 0.f};
        if (ce == 4) {
            // prefetch all 8 index quads (independent LDS reads)
            int4 r[PATH_LEN];
#pragma unroll
            for (int l = 0; l < PATH_LEN; ++l)
                r[l] = *(const int4*)&idx_l[node][e][l][0];
            // two batches of 16 independent global loads each
#pragma unroll
            for (int half = 0; half < 2; ++half) {
                uint2 g[4][4];
#pragma unroll
                for (int l = 0; l < 4; ++l) {
                    int4 rr = r[half * 4 + l];
                    g[l][0] = *(const uint2*)(feats_u + (long)rr.x * 64 + coff);
                    g[l][1] = *(const uint2*)(feats_u + (long)rr.y * 64 + coff);
                    g[l][2] = *(const uint2*)(feats_u + (long)rr.z * 64 + coff);
                    g[l][3] = *(const uint2*)(feats_u + (long)rr.w * 64 + coff);
                }
#pragma unroll
                for (int l = 0; l < 4; ++l) {
                    float sx = bf2f((ushort)(g[l][0].x & 0xffff)) + bf2f((ushort)(g[l][1].x & 0xffff))
                             + bf2f((ushort)(g[l][2].x & 0xffff)) + bf2f((ushort)(g[l][3].x & 0xffff));
                    float sy = bf2f((ushort)(g[l][0].x >> 16)) + bf2f((ushort)(g[l][1].x >> 16))
                             + bf2f((ushort)(g[l][2].x >> 16)) + bf2f((ushort)(g[l][3].x >> 16));
                    float sz = bf2f((ushort)(g[l][0].y & 0xffff)) + bf2f((ushort)(g[l][1].y & 0xffff))
                             + bf2f((ushort)(g[l][2].y & 0xffff)) + bf2f((ushort)(g[l][3].y & 0xffff));
                    float sw = bf2f((ushort)(g[l][0].y >> 16)) + bf2f((ushort)(g[l][1].y >> 16))
                             + bf2f((ushort)(g[l][2].y >> 16)) + bf2f((ushort)(g[l][3].y >> 16));
                    const float4 wv = *(const float4*)&wls[e][half * 4 + l][l16 * 4];
                    acc.x += sx * wv.x;
                    acc.y += sy * wv.y;
                    acc.z += sz * wv.z;
                    acc.w += sw * wv.w;
                }
            }
        } else {
            // generic fallback for any type distribution
#pragma unroll
            for (int l = 0; l < PATH_LEN; ++l) {
                float sx = 0.f, sy = 0.f, sz = 0.f, sw = 0.f;
                for (int q = 0; q < ce; ++q) {
                    int row = idx_l[node][e][l][q];
                    uint2 v = *(const uint2*)(feats_u + (long)row * 64 + coff);
                    sx += bf2f((ushort)(v.x & 0xffff));
                    sy += bf2f((ushort)(v.x >> 16));
                    sz += bf2f((ushort)(v.y & 0xffff));
                    sw += bf2f((ushort)(v.y >> 16));
                }
                const float4 wv = *(const float4*)&wls[e][l][l16 * 4];
                acc.x += sx * wv.x;
                acc.y += sy * wv.y;
                acc.z += sz * wv.z;
                acc.w += sw * wv.w;
            }
        }
        out[e] = acc;
    }

#pragma unroll
    for (int e = 0; e < 2; ++e) {
        uint2 o;
        o.x = (uint)f2bf(out[e].x) | ((uint)f2bf(out[e].y) << 16);
        o.y = (uint)f2bf(out[e].z) | ((uint)f2bf(out[e].w) << 16);
        unsigned long long packed = (unsigned long long)o.x
                                  | ((unsigned long long)o.y << 32);
        __builtin_nontemporal_store(packed,
            (unsigned long long*)(fout_u + (long)n * 128 + e * 64 + coff));
    }
}

// ---------------------------------------------------------------------------
extern "C" void kernel_launch(void* const* d_in, const int* in_sizes, int n_in,
                              void* d_out, int out_size, void* d_ws, size_t ws_size,
                              hipStream_t stream)
{
    const float* input_x      = (const float*)d_in[0];
    const int*   paths        = (const int*)d_in[1];
    const int*   path_types   = (const int*)d_in[2];
    const float* fc_in_w      = (const float*)d_in[3];
    const float* fc_in_b      = (const float*)d_in[4];
    const float* fc_out_w     = (const float*)d_in[5];
    const float* fc_out_b     = (const float*)d_in[6];
    const float* layer_fc_w   = (const float*)d_in[7];
    const float* path_weights = (const float*)d_in[8];
    float* out = (float*)d_out;

    char* p = (char*)d_ws;
    ushort* w_in     = (ushort*)p; p += HID * IN_DIM * 2;                   // 64 KB
    ushort* w_layer  = (ushort*)p; p += N_LAYERS * HID * N_TYPES * HID * 2; // 256 KB
    ushort* w_out    = (ushort*)p; p += OUT_DIM * HID * 2;                  // 16 KB
    ushort* in_feats = (ushort*)p; p += (long)NN * HID * 2;                 // 5.12 MB
    ushort* featsA   = (ushort*)p; p += (long)NN * HID * 2;
    ushort* featsB   = (ushort*)p; p += (long)NN * HID * 2;
    ushort* fout     = (ushort*)p; p += (long)NN * N_TYPES * HID * 2;       // 10.24 MB

    cvt_weights<<<168, 256, 0, stream>>>(fc_in_w, layer_fc_w, fc_out_w,
                                         w_in, w_layer, w_out);

    const int GG = (NN + 63) / 64;          // 313
    const int GATHER_GRID = (NN / 16) * 2;  // 2500

    gemm_mfma<HID, IN_DIM, 0, true><<<GG, 256, 0, stream>>>(
        input_x, w_in, fc_in_b, nullptr, nullptr, in_feats, NN);

    const ushort* src = in_feats;
    ushort* dsts[N_LAYERS] = {featsA, featsB, featsA, featsB};
    for (int i = 0; i < N_LAYERS; ++i) {
        gather_bf16<<<GATHER_GRID, 256, 0, stream>>>(
            (const uint*)src, paths, path_types,
            path_weights + (long)i * N_TYPES * PATH_LEN * HID, (uint*)fout);
        gemm_mfma<HID, N_TYPES * HID, 1, false><<<GG, 256, 0, stream>>>(
            fout, w_layer + (long)i * HID * N_TYPES * HID, nullptr,
            src, in_feats, dsts[i], NN);
        src = dsts[i];
    }

    gemm_mfma<OUT_DIM, HID, 2, false><<<GG, 256, 0, stream>>>(
        src, w_out, fc_out_b, nullptr, nullptr, out, NN);
}